// Round 5
// baseline (32.783 us; speedup 1.0000x reference)
//
#include <hip/hip_runtime.h>
#include <cstdint>
#include <math.h>

#define N_FRAMES 16777216            // 2^24
#define MAX_BEATS (N_FRAMES / 8)     // 2097152
#define NTHREADS 256
#define EPT 32                       // elems per thread
#define EPB (NTHREADS * EPT)         // 8192 elems per block
#define NBLOCKS (N_FRAMES / EPB)     // 2048
#define WCHUNK 2048                  // elems per wave-chunk (64 lanes * 32)
#define NWCHUNK (N_FRAMES / WCHUNK)  // 8192
#define NMASK32 (N_FRAMES / 32)      // 524288 u32 masks

typedef unsigned int u32;

// k_count: 32 elems/thread, halo via shfl, no LDS, no syncthreads.
__global__ __launch_bounds__(NTHREADS) void k_count(const float* __restrict__ x,
                                                    int* __restrict__ counts,
                                                    u32* __restrict__ masks) {
  const int t = threadIdx.x;
  const int lane = t & 63;
  const int wv = t >> 6;
  const int q = blockIdx.x * 4 + wv;               // wave-chunk id
  const int gbase = q * WCHUNK + lane * EPT;

  // v[k] = x[gbase - 4 + k], k in [0,40)
  float v[40];
  const float4* p = reinterpret_cast<const float4*>(x + gbase);
#pragma unroll
  for (int k = 0; k < 8; ++k) {
    const float4 f = p[k];
    v[4 + 4 * k] = f.x; v[5 + 4 * k] = f.y; v[6 + 4 * k] = f.z; v[7 + 4 * k] = f.w;
  }
#pragma unroll
  for (int j = 0; j < 4; ++j) v[j] = __shfl_up(v[32 + j], 1, 64);
#pragma unroll
  for (int j = 0; j < 4; ++j) v[36 + j] = __shfl_down(v[4 + j], 1, 64);
  if (lane == 0) {
    if (gbase >= 4) {
      const float4 f = *reinterpret_cast<const float4*>(x + gbase - 4);
      v[0] = f.x; v[1] = f.y; v[2] = f.z; v[3] = f.w;
    } else {
      v[0] = v[1] = v[2] = v[3] = -INFINITY;       // start of array
    }
  }
  if (lane == 63) {
    if (gbase + 36 <= N_FRAMES) {
      const float4 f = *reinterpret_cast<const float4*>(x + gbase + 32);
      v[36] = f.x; v[37] = f.y; v[38] = f.z; v[39] = f.w;
    } else {
      v[36] = v[37] = v[38] = v[39] = -INFINITY;   // end of array
    }
  }

  // trio maxes: Lt[i] = max(v[i],v[i+1],v[i+2]); window(e) = max(Lt[e+1], Lt[e+5])
  float Lt[37];
#pragma unroll
  for (int i = 0; i < 37; ++i) Lt[i] = fmaxf(fmaxf(v[i], v[i + 1]), v[i + 2]);

  u32 pm = 0;
#pragma unroll
  for (int e = 0; e < 32; ++e) {
    const float c = v[e + 4];
    const float m = fmaxf(Lt[e + 1], Lt[e + 5]);
    if (c > 0.0f && c >= m) pm |= (1u << e);
  }
  masks[q * 64 + lane] = pm;

  u32 prevbit = __shfl_up(pm, 1, 64) >> 31;
  if (lane == 0) {   // peak at gbase-1: center v[3], trios Lt[0], Lt[4]
    const float c = v[3];
    const float m = fmaxf(Lt[0], Lt[4]);
    prevbit = (c > 0.0f && c >= m) ? 1u : 0u;
  }
  const u32 sm = pm & ~((pm << 1) | prevbit);
  int cnt = __popc(sm);
#pragma unroll
  for (int off = 32; off; off >>= 1) cnt += __shfl_down(cnt, off, 64);
  if (lane == 0) counts[q] = cnt;
}

// k_emit: block handles 4 wave-chunks; inlines the global prefix over counts.
__global__ __launch_bounds__(NTHREADS) void k_emit(const u32* __restrict__ masks,
                                                   const int* __restrict__ counts,
                                                   float* __restrict__ out) {
  __shared__ int s_wtot[4];
  __shared__ int s_excl0[NTHREADS];  // wave-local exclusive prefix of thread sums
  __shared__ int s_off[4];
  __shared__ int s_total;
  const int t = threadIdx.x;
  const int lane = t & 63;
  const int wv = t >> 6;

  // global scan recompute: thread t owns counts[32t .. 32t+32)
  int s = 0;
#pragma unroll
  for (int e = 0; e < 32; ++e) s += counts[t * 32 + e];
  int incl = s;
#pragma unroll
  for (int off = 1; off < 64; off <<= 1) {
    const int vv = __shfl_up(incl, off, 64);
    if (lane >= off) incl += vv;
  }
  s_excl0[t] = incl - s;
  if (lane == 63) s_wtot[wv] = incl;
  __syncthreads();
  if (t == 0) s_total = s_wtot[0] + s_wtot[1] + s_wtot[2] + s_wtot[3];
  const int base = blockIdx.x * 4;
  if (t < 4) {     // compute offset of wave-chunk base+t
    const int target = base + t;
    const int j = target >> 5, r = target & 31;
    int wb = 0;
    for (int ww = 0; ww < (j >> 6); ++ww) wb += s_wtot[ww];
    int pfx = wb + s_excl0[j];
    for (int e = 0; e < r; ++e) pfx += counts[j * 32 + e];
    s_off[t] = pfx;
  }
  __syncthreads();

  const int q = base + wv;
  const u32 m = masks[q * 64 + lane];
  u32 prevbit = __shfl_up(m, 1, 64) >> 31;
  if (lane == 0) prevbit = (q == 0) ? 0u : (masks[q * 64 - 1] >> 31);
  u32 sm = m & ~((m << 1) | prevbit);
  const int cnt = __popc(sm);

  int incl2 = cnt;
#pragma unroll
  for (int off = 1; off < 64; off <<= 1) {
    const int vv = __shfl_up(incl2, off, 64);
    if (lane >= off) incl2 += vv;
  }
  int sid = s_off[wv] + incl2 - cnt;

  const int gbase = q * WCHUNK + lane * 32;
  while (sm) {
    const int sb = __builtin_ctz(sm);
    sm &= sm - 1;
    const int i0 = gbase + sb;
    const u32 above = m >> sb;           // bit 0 = this peak
    const int len = (~above == 0u) ? (32 - sb) : __builtin_ctz(~above);
    int end = i0 + len - 1;
    if (sb + len == 32) {                // run continues into next mask (ties; rare)
      int idx = q * 64 + lane + 1;
      while (idx < NMASK32) {
        const u32 mm = masks[idx];
        if (~mm == 0u) { end += 32; ++idx; }
        else { end += __builtin_ctz(~mm); break; }
      }
    }
    if (sid < MAX_BEATS)
      out[sid] = (float)(((double)i0 + (double)end) * 0.5);
    ++sid;
  }

  // -1 tail fill: this block covers out[blockIdx*1024 .. +1024)
  const int lo = blockIdx.x * (MAX_BEATS / NBLOCKS);
  const int hi = lo + (MAX_BEATS / NBLOCKS);
  for (int i = max(lo, s_total) + t; i < hi; i += NTHREADS)
    out[i] = -1.0f;
}

extern "C" void kernel_launch(void* const* d_in, const int* in_sizes, int n_in,
                              void* d_out, int out_size, void* d_ws, size_t ws_size,
                              hipStream_t stream) {
  const float* x = (const float*)d_in[0];
  float* out = (float*)d_out;

  u32* masks = (u32*)d_ws;                   // 2 MiB
  int* counts = (int*)(masks + NMASK32);     // 32 KiB

  k_count<<<NBLOCKS, NTHREADS, 0, stream>>>(x, counts, masks);
  k_emit<<<NBLOCKS, NTHREADS, 0, stream>>>(masks, counts, out);
}